// Round 2
// baseline (3110.312 us; speedup 1.0000x reference)
//
#include <hip/hip_runtime.h>

typedef unsigned short u16;
typedef unsigned int u32;
typedef __bf16 bf16x8 __attribute__((ext_vector_type(8)));
typedef float floatx4 __attribute__((ext_vector_type(4)));

#define B_ 8
#define S_ 1024
#define D_ 1024
#define H_ 16
#define NREL 65  // 2*MAXREL+1

__device__ __forceinline__ float b2f(u16 u) { return __uint_as_float(((u32)u) << 16); }
__device__ __forceinline__ u16 f2b(float f) {
    u32 x = __float_as_uint(f);
    x += 0x7fffu + ((x >> 16) & 1u);  // RNE
    return (u16)(x >> 16);
}

// ---------------- 1024x1024 transpose: f32 in -> bf16 out (W -> W^T) ----------------
__global__ __launch_bounds__(256) void transpose_w(const float* __restrict__ in,
                                                   u16* __restrict__ out) {
    __shared__ u16 tile[32][33];
    int c0 = blockIdx.x * 32, r0 = blockIdx.y * 32;
    int tx = threadIdx.x & 31, ty = threadIdx.x >> 5;
#pragma unroll
    for (int i = 0; i < 32; i += 8)
        tile[ty + i][tx] = f2b(in[(size_t)(r0 + ty + i) * 1024 + c0 + tx]);
    __syncthreads();
#pragma unroll
    for (int i = 0; i < 32; i += 8)
        out[(size_t)(c0 + ty + i) * 1024 + r0 + tx] = tile[tx][ty + i];
}

// ---------------- GEMM: C[M,1024] = A[M,K] @ WT[1024,K]^T + bias ----------------
// A is f32 (a_bf16=0) or bf16 (a_bf16=1); WT is bf16.
// mode 0: outf[row*1024+col] (f32)     mode 1: outb[((b*H+h)*S+s)*64+d] (bf16 head-major)
__global__ __launch_bounds__(256, 2) void gemm_bt(
    const void* __restrict__ Av, const u16* __restrict__ WT, const float* __restrict__ bias,
    float* __restrict__ outf, u16* __restrict__ outb, int M, int K, int mode, int a_bf16,
    float scale) {
    __shared__ __align__(16) u16 As[128 * 64];
    __shared__ __align__(16) u16 Bs[128 * 64];
    int tid = threadIdx.x;
    int wave = tid >> 6, lane = tid & 63;
    int wm = (wave >> 1) * 64, wn = (wave & 1) * 64;
    int m0 = blockIdx.y * 128, n0 = blockIdx.x * 128;
    floatx4 acc[4][4] = {};
    for (int kt = 0; kt < K; kt += 64) {
        if (a_bf16) {
            const u16* A = (const u16*)Av;
#pragma unroll
            for (int i = 0; i < 4; i++) {
                int L = tid + 256 * i;
                int row = L >> 3, seg = (L & 7) * 8;
                *(uint4*)(As + row * 64 + seg) = *(const uint4*)(A + (size_t)(m0 + row) * K + kt + seg);
            }
        } else {
            const float* A = (const float*)Av;
#pragma unroll
            for (int i = 0; i < 8; i++) {
                int L = tid + 256 * i;
                int row = L >> 4, seg = (L & 15) * 4;
                float4 a = *(const float4*)(A + (size_t)(m0 + row) * K + kt + seg);
                ushort4 b;
                b.x = f2b(a.x); b.y = f2b(a.y); b.z = f2b(a.z); b.w = f2b(a.w);
                *(ushort4*)(As + row * 64 + seg) = b;
            }
        }
#pragma unroll
        for (int i = 0; i < 4; i++) {
            int L = tid + 256 * i;
            int row = L >> 3, seg = (L & 7) * 8;
            *(uint4*)(Bs + row * 64 + seg) = *(const uint4*)(WT + (size_t)(n0 + row) * K + kt + seg);
        }
        __syncthreads();
        int kb = (lane >> 4) * 8;
#pragma unroll
        for (int half = 0; half < 2; half++) {
            bf16x8 af[4], bfv[4];
#pragma unroll
            for (int mi = 0; mi < 4; mi++)
                af[mi] = *(const bf16x8*)(As + (wm + mi * 16 + (lane & 15)) * 64 + half * 32 + kb);
#pragma unroll
            for (int ni = 0; ni < 4; ni++)
                bfv[ni] = *(const bf16x8*)(Bs + (wn + ni * 16 + (lane & 15)) * 64 + half * 32 + kb);
#pragma unroll
            for (int mi = 0; mi < 4; mi++)
#pragma unroll
                for (int ni = 0; ni < 4; ni++)
                    acc[mi][ni] = __builtin_amdgcn_mfma_f32_16x16x32_bf16(af[mi], bfv[ni], acc[mi][ni], 0, 0, 0);
        }
        __syncthreads();
    }
    int lr = (lane >> 4) * 4, lc = lane & 15;
#pragma unroll
    for (int mi = 0; mi < 4; mi++) {
#pragma unroll
        for (int ni = 0; ni < 4; ni++) {
            int col = n0 + wn + ni * 16 + lc;
            float bv = bias[col];
#pragma unroll
            for (int r = 0; r < 4; r++) {
                int row = m0 + wm + mi * 16 + lr + r;
                float v = (acc[mi][ni][r] + bv) * scale;
                if (mode == 0) {
                    outf[(size_t)row * 1024 + col] = v;
                } else {
                    int b = row >> 10, s = row & 1023;
                    int hh = col >> 6, d = col & 63;
                    outb[(((size_t)(b * H_ + hh)) * S_ + s) * 64 + d] = f2b(v);
                }
            }
        }
    }
}

// ---------------- fused attention ----------------
// one block = (b, h, 8 q-rows); 256 threads
__global__ __launch_bounds__(256, 2) void attn_fused(
    const u16* __restrict__ qw, const u16* __restrict__ kw, const u16* __restrict__ vw,
    const int* __restrict__ mask, const float* __restrict__ adj,
    const float* __restrict__ relk, const float* __restrict__ relv,
    float* __restrict__ attn_out, u16* __restrict__ ctx) {
    __shared__ __align__(16) float s_sc[8 * 1024];   // scores -> attn (f32)
    __shared__ __align__(16) float s_q[8 * 64];      // scaled q rows
    __shared__ __align__(16) float s_qrel[8 * 65];   // q . rel_k[v]
    __shared__ __align__(16) float s_rv[65 * 66];    // rel_v, padded stride
    __shared__ __align__(16) float s_rk[65 * 65];    // rel_k; later reused as V tile (u16[128*64])
    __shared__ __align__(16) float s_arel[8 * 65];   // bucketed attn sums

    const int tid = threadIdx.x;
    const int q0 = blockIdx.x * 8;
    const int h = blockIdx.y, b = blockIdx.z;
    const size_t bh = (size_t)b * H_ + h;
    const u16* qb = qw + bh * S_ * 64;
    const u16* kbp = kw + bh * S_ * 64;
    const u16* vb = vw + bh * S_ * 64;

    for (int i = tid; i < NREL * 64; i += 256) {
        int v = i >> 6, d = i & 63;
        s_rk[v * 65 + d] = relk[i];
        s_rv[v * 66 + d] = relv[i];
    }
    for (int i = tid; i < 8 * 64; i += 256) s_q[i] = b2f(qb[(size_t)q0 * 64 + i]);
    __syncthreads();

    // qrel[r][v] = sum_d q[r][d]*rel_k[v][d]
    for (int i = tid; i < 8 * 65; i += 256) {
        int r = i / 65, v = i - r * 65;
        float a = 0.f;
        for (int d = 0; d < 64; d++) a += s_q[r * 64 + d] * s_rk[v * 65 + d];
        s_qrel[i] = a;
    }
    __syncthreads();

    // ---- Phase A: scores (4 rows x 8 kp per thread) ----
    {
        const int rg = tid >> 7;      // 0..1
        const int cg = tid & 127;     // 0..127
        const int r0 = rg * 4;
        float acc[4][8];
#pragma unroll
        for (int r = 0; r < 4; r++)
#pragma unroll
            for (int j = 0; j < 8; j++) acc[r][j] = 0.f;
        for (int dc = 0; dc < 64; dc += 8) {
            float qr[4][8];
#pragma unroll
            for (int r = 0; r < 4; r++) {
                float4 a0 = *(const float4*)&s_q[(r0 + r) * 64 + dc];
                float4 a1 = *(const float4*)&s_q[(r0 + r) * 64 + dc + 4];
                qr[r][0] = a0.x; qr[r][1] = a0.y; qr[r][2] = a0.z; qr[r][3] = a0.w;
                qr[r][4] = a1.x; qr[r][5] = a1.y; qr[r][6] = a1.z; qr[r][7] = a1.w;
            }
#pragma unroll
            for (int j = 0; j < 8; j++) {
                int kp = cg + 128 * j;
                uint4 kw4 = *(const uint4*)(kbp + (size_t)kp * 64 + dc);
                float kf[8];
                kf[0] = __uint_as_float(kw4.x << 16); kf[1] = __uint_as_float(kw4.x & 0xffff0000u);
                kf[2] = __uint_as_float(kw4.y << 16); kf[3] = __uint_as_float(kw4.y & 0xffff0000u);
                kf[4] = __uint_as_float(kw4.z << 16); kf[5] = __uint_as_float(kw4.z & 0xffff0000u);
                kf[6] = __uint_as_float(kw4.w << 16); kf[7] = __uint_as_float(kw4.w & 0xffff0000u);
#pragma unroll
                for (int r = 0; r < 4; r++)
#pragma unroll
                    for (int d = 0; d < 8; d++) acc[r][j] += qr[r][d] * kf[d];
            }
        }
#pragma unroll
        for (int r = 0; r < 4; r++) {
            int qp = q0 + r0 + r;
            const int* mrow = mask + ((size_t)b * S_ + qp) * S_;
            const float* arow = adj + (bh * S_ + qp) * S_;
#pragma unroll
            for (int j = 0; j < 8; j++) {
                int kp = cg + 128 * j;
                int dd = kp - qp;
                dd = max(-32, min(32, dd));
                float sc = acc[r][j] + s_qrel[(r0 + r) * 65 + dd + 32];
                int mk = mrow[kp];
                float aj = arow[kp];
                if (mk != 0 || aj == 0.f) sc = -1e18f;
                s_sc[(r0 + r) * 1024 + kp] = sc;
            }
        }
    }
    __syncthreads();

    // ---- Phase B: softmax + adj renorm (32-lane group per row) ----
    const int row = tid >> 5, sub = tid & 31;
    const int qpos = q0 + row;
    const float* arow = adj + (bh * S_ + qpos) * S_;
    float* orow = attn_out + (bh * S_ + qpos) * S_;
    float m = -3.0e38f;
    for (int i = 0; i < 32; i++) m = fmaxf(m, s_sc[row * 1024 + sub + 32 * i]);
#pragma unroll
    for (int o = 16; o > 0; o >>= 1) m = fmaxf(m, __shfl_xor(m, o));
    float psum = 0.f, pisum = 0.f;
    for (int i = 0; i < 32; i++) {
        int kp = sub + 32 * i;
        float p = __expf(s_sc[row * 1024 + kp] - m);
        float aj = arow[kp];
        float inv = (aj != 0.f) ? (1.f / aj) : 1e-18f;
        float pi = p * inv;
        s_sc[row * 1024 + kp] = pi;
        psum += p; pisum += pi;
    }
#pragma unroll
    for (int o = 16; o > 0; o >>= 1) { psum += __shfl_xor(psum, o); pisum += __shfl_xor(pisum, o); }
    float rden = 1.f / fmaxf(pisum, 1e-12f * psum);
    for (int i = 0; i < 32; i++) {
        int kp = sub + 32 * i;
        float at = s_sc[row * 1024 + kp] * rden;
        s_sc[row * 1024 + kp] = at;
        orow[kp] = at;
    }
    __syncthreads();

    // ---- Phase C: ctx = attn @ V (V staged in LDS tiles) + bucketed rel_v term ----
    const int d0 = sub * 2;
    u16* s_vt = (u16*)s_rk;  // reuse rel_k space (16384B needed, 16900B avail)
    float c0 = 0.f, c1 = 0.f;
    for (int kt = 0; kt < 1024; kt += 128) {
        __syncthreads();
        const uint4* src = (const uint4*)(vb + (size_t)kt * 64);
        uint4* dst = (uint4*)s_vt;
        for (int l = tid; l < 1024; l += 256) dst[l] = src[l];
        __syncthreads();
#pragma unroll 4
        for (int kk = 0; kk < 128; kk++) {
            float a = s_sc[row * 1024 + kt + kk];
            u32 vv = *(const u32*)(s_vt + kk * 64 + d0);
            c0 += a * __uint_as_float(vv << 16);
            c1 += a * __uint_as_float(vv & 0xffff0000u);
        }
    }
    // bucket attn into 65 rel-distance bins
    float s0 = 0.f;
    for (int k = sub; k <= qpos - 32; k += 32) s0 += s_sc[row * 1024 + k];
#pragma unroll
    for (int o = 16; o > 0; o >>= 1) s0 += __shfl_xor(s0, o);
    if (sub == 0) s_arel[row * 65 + 0] = s0;
    float s1 = 0.f;
    for (int k = qpos + 32 + sub; k < 1024; k += 32) s1 += s_sc[row * 1024 + k];
#pragma unroll
    for (int o = 16; o > 0; o >>= 1) s1 += __shfl_xor(s1, o);
    if (sub == 0) s_arel[row * 65 + 64] = s1;
    for (int i = sub; i < 63; i += 32) {
        int v = 1 + i;
        int k = qpos + v - 32;
        s_arel[row * 65 + v] = (k >= 0 && k < 1024) ? s_sc[row * 1024 + k] : 0.f;
    }
    __syncthreads();
    for (int v = 0; v < 65; v++) {
        float ar = s_arel[row * 65 + v];
        c0 += ar * s_rv[v * 66 + d0];
        c1 += ar * s_rv[v * 66 + d0 + 1];
    }
    u32 packed = (u32)f2b(c0) | ((u32)f2b(c1) << 16);
    *(u32*)(ctx + ((size_t)(b * S_ + qpos)) * 1024 + h * 64 + d0) = packed;
}

extern "C" void kernel_launch(void* const* d_in, const int* in_sizes, int n_in,
                              void* d_out, int out_size, void* d_ws, size_t ws_size,
                              hipStream_t stream) {
    const float* key   = (const float*)d_in[0];
    const float* value = (const float*)d_in[1];
    const float* query = (const float*)d_in[2];
    const int* mask    = (const int*)d_in[3];   // bool in ref -> int32 upload
    const float* adj   = (const float*)d_in[4];
    const float* Wq = (const float*)d_in[5];  const float* bq = (const float*)d_in[6];
    const float* Wk = (const float*)d_in[7];  const float* bk = (const float*)d_in[8];
    const float* Wv = (const float*)d_in[9];  const float* bv = (const float*)d_in[10];
    const float* Wo = (const float*)d_in[11]; const float* bo = (const float*)d_in[12];
    const float* relk = (const float*)d_in[13];
    const float* relv = (const float*)d_in[14];

    float* out_final = (float*)d_out;
    float* out_attn  = out_final + (size_t)B_ * S_ * D_;

    char* ws = (char*)d_ws;
    u16* wt  = (u16*)ws;                               // 2MB transposed weight (bf16)
    u16* qws = (u16*)(ws + ((size_t)2 << 20));         // [B,H,S,64] bf16, 16MB
    u16* kws = (u16*)(ws + ((size_t)18 << 20));        // 16MB
    u16* vws = (u16*)(ws + ((size_t)34 << 20));        // 16MB
    u16* cws = (u16*)(ws + ((size_t)50 << 20));        // ctx [B*S, H*64] bf16 16MB

    dim3 tg(32, 32), tb(256);
    dim3 gg(8, 64), gb(256);
    dim3 ag(128, 16, 8), ab(256);

    transpose_w<<<tg, tb, 0, stream>>>(Wq, wt);
    gemm_bt<<<gg, gb, 0, stream>>>(query, wt, bq, nullptr, qws, 8192, 1024, 1, 0, 0.125f);
    transpose_w<<<tg, tb, 0, stream>>>(Wk, wt);
    gemm_bt<<<gg, gb, 0, stream>>>(key, wt, bk, nullptr, kws, 8192, 1024, 1, 0, 1.0f);
    transpose_w<<<tg, tb, 0, stream>>>(Wv, wt);
    gemm_bt<<<gg, gb, 0, stream>>>(value, wt, bv, nullptr, vws, 8192, 1024, 1, 0, 1.0f);
    attn_fused<<<ag, ab, 0, stream>>>(qws, kws, vws, mask, adj, relk, relv, out_attn, cws);
    transpose_w<<<tg, tb, 0, stream>>>(Wo, wt);
    gemm_bt<<<gg, gb, 0, stream>>>(cws, wt, bo, out_final, nullptr, 8192, 1024, 0, 1, 1.0f);
}